// Round 1
// baseline (249.140 us; speedup 1.0000x reference)
//
#include <hip/hip_runtime.h>

typedef __attribute__((ext_vector_type(8))) short short8;
typedef __attribute__((ext_vector_type(4))) float f32x4;
typedef __attribute__((ext_vector_type(4))) int i32x4;

#define NN 8192
#define ALPHA 0.2f

__device__ __forceinline__ float bf16_to_f32(unsigned short h) {
    union { unsigned int u; float f; } c;
    c.u = ((unsigned int)h) << 16;
    return c.f;
}
__device__ __forceinline__ unsigned short f32_to_bf16(float f) {
    union { float f; unsigned int u; } c;
    c.f = f;
    unsigned int r = (c.u + 0x7FFFu + ((c.u >> 16) & 1u)) >> 16;
    return (unsigned short)r;
}

// ---------------- kernel 0: probe input dtype -------------------------------
// Interpret first 64K halves of X as bf16. If X really is bf16 normal data,
// ~100% of values are finite with |v| in (1e-6, 64). If X is f32 normal data,
// only the high halves look sane (~55% pass). Writes flag: 1 = inputs bf16.
__global__ void gat_probe_dtype(const unsigned short* __restrict__ x16, int* flag) {
    __shared__ int cnts[256];
    int tid = threadIdx.x;
    int cnt = 0;
    for (int i = tid; i < 65536; i += 256) {
        float v = bf16_to_f32(x16[i]);
        float a = fabsf(v);
        if (a > 1e-6f && a < 64.0f) cnt++;   // false for NaN too
    }
    cnts[tid] = cnt;
    __syncthreads();
    for (int s = 128; s > 0; s >>= 1) {
        if (tid < s) cnts[tid] += cnts[tid + s];
        __syncthreads();
    }
    if (tid == 0) *flag = (cnts[0] > 52000) ? 1 : 0;
}

// ---------------- kernel 1: convert inputs to ws copies ---------------------
__global__ void gat_convert(const void* __restrict__ Xv, const void* __restrict__ Wv,
                            const void* __restrict__ bv, const void* __restrict__ asv,
                            const void* __restrict__ arv,
                            short* __restrict__ Xb, short* __restrict__ Wb,
                            float* __restrict__ bF, float* __restrict__ asF,
                            float* __restrict__ arF, const int* __restrict__ flag) {
    const int NX = NN * 256, NW = 256 * 256, NS = 256;
    const int total = NX + NW + 3 * NS;
    const int isBf = *flag;
    for (int i = blockIdx.x * blockDim.x + threadIdx.x; i < total;
         i += gridDim.x * blockDim.x) {
        if (i < NX) {
            Xb[i] = isBf ? (short)((const unsigned short*)Xv)[i]
                         : (short)f32_to_bf16(((const float*)Xv)[i]);
        } else if (i < NX + NW) {
            int j = i - NX;
            Wb[j] = isBf ? (short)((const unsigned short*)Wv)[j]
                         : (short)f32_to_bf16(((const float*)Wv)[j]);
        } else {
            int j = i - NX - NW;
            int which = j >> 8;
            int k = j & 255;
            const void* src = (which == 0) ? bv : (which == 1) ? asv : arv;
            float v = isBf ? bf16_to_f32(((const unsigned short*)src)[k])
                           : ((const float*)src)[k];
            float* dst = (which == 0) ? bF : (which == 1) ? asF : arF;
            dst[k] = v;
        }
    }
}

// ---------------- kernel 2: H_in = X*W^T + b, s, r, Ht ----------------------
// MFMA 16x16x32 bf16, operands straight from global (L2-hot).
// Block: 256 thr = 4 waves; wave w handles rows blockIdx*64 + w*16 .. +15,
// all 256 cols. Writes Ht[col][row] (bf16, transposed for PV B-operand),
// s[row], r[row] (f32).
__global__ __launch_bounds__(256) void gat_gemm1(
    const short* __restrict__ Xb, const short* __restrict__ Wb,
    const float* __restrict__ bF, const float* __restrict__ asF,
    const float* __restrict__ arF,
    short* __restrict__ Ht, float* __restrict__ sOut, float* __restrict__ rOut) {
    const int tid = threadIdx.x;
    const int wave = tid >> 6, lane = tid & 63;
    const int l15 = lane & 15, lhi = lane >> 4;
    const int rowBase = blockIdx.x * 64 + wave * 16;

    f32x4 acc[16];
#pragma unroll
    for (int n = 0; n < 16; n++) acc[n] = (f32x4){0.f, 0.f, 0.f, 0.f};

    const short8* Xrow = (const short8*)(Xb + (size_t)(rowBase + l15) * 256);
#pragma unroll
    for (int ks = 0; ks < 8; ks++) {            // K = 256 in steps of 32
        short8 a = Xrow[ks * 4 + lhi];          // A[row=l15][k=ks*32+8*lhi ..+7]
#pragma unroll
        for (int n = 0; n < 16; n++) {
            const short8* Wrow = (const short8*)(Wb + (size_t)(n * 16 + l15) * 256);
            short8 bf = Wrow[ks * 4 + lhi];     // B[k][col=l15] = W[col][k]
            acc[n] = __builtin_amdgcn_mfma_f32_16x16x32_bf16(a, bf, acc[n], 0, 0, 0);
        }
    }

    float sPart[4] = {0.f, 0.f, 0.f, 0.f};
    float rPart[4] = {0.f, 0.f, 0.f, 0.f};
#pragma unroll
    for (int n = 0; n < 16; n++) {
        int col = n * 16 + l15;
        float bias = bF[col], asc = asF[col], arc = arF[col];
#pragma unroll
        for (int q = 0; q < 4; q++) {
            float h = acc[n][q] + bias;         // D: row=lhi*4+q, col=l15 (m89)
            int row = rowBase + lhi * 4 + q;
            Ht[(size_t)col * NN + row] = (short)f32_to_bf16(h);
            sPart[q] += h * asc;
            rPart[q] += h * arc;
        }
    }
#pragma unroll
    for (int m = 1; m <= 8; m <<= 1) {
#pragma unroll
        for (int q = 0; q < 4; q++) {
            sPart[q] += __shfl_xor(sPart[q], m, 64);
            rPart[q] += __shfl_xor(rPart[q], m, 64);
        }
    }
    if (l15 == 0) {
#pragma unroll
        for (int q = 0; q < 4; q++) {
            int row = rowBase + lhi * 4 + q;
            sOut[row] = sPart[q];
            rOut[row] = rPart[q];
        }
    }
}

// ---------------- kernel 3: fused masked-softmax PV -------------------------
// Block: rows i0..i0+31. Wave w owns cols [w*64, w*64+64) == head w.
// K-loop (128 tiles of 64): generate P = A ? exp(lrelu(s_i+r_j)) : 0 into LDS
// (bf16), stage Ht tile into LDS, MFMA-accumulate; divide by row-sum at end,
// sum the 4 heads across waves via LDS.
__global__ __launch_bounds__(256) void gat_pv(
    const int* __restrict__ A, const short* __restrict__ Ht,
    const float* __restrict__ sV, const float* __restrict__ rV,
    const int* __restrict__ flag, void* __restrict__ outP) {
    __shared__ __align__(16) short HtL[256][72];   // [col][k], pad 8 -> 144B pitch
    __shared__ __align__(16) short PL[32][72];     // [row][k]
    __shared__ float denomL[32];
    __shared__ float outL[4][32][64];

    const int tid = threadIdx.x;
    const int wave = tid >> 6, lane = tid & 63;
    const int l15 = lane & 15, lhi = lane >> 4;
    const int i0 = blockIdx.x * 32;
    const int pr = tid >> 3;            // P-gen row 0..31
    const int pc = (tid & 7) * 8;       // P-gen col base

    const float sMine = sV[i0 + pr];
    float dsum = 0.f;

    f32x4 acc[2][4];
#pragma unroll
    for (int m = 0; m < 2; m++)
#pragma unroll
        for (int n = 0; n < 4; n++) acc[m][n] = (f32x4){0.f, 0.f, 0.f, 0.f};

    const size_t arowOff = (size_t)(i0 + pr) * NN;

    for (int kt = 0; kt < 128; kt++) {
        const int k0 = kt * 64;
        // stage Ht tile: [256 cols][64 k]
        {
            const int cBase = tid >> 3;
            const int kc = (tid & 7) * 8;
#pragma unroll
            for (int j = 0; j < 8; j++) {
                int c = cBase + 32 * j;
                short8 v = *(const short8*)(Ht + (size_t)c * NN + k0 + kc);
                *(short8*)(&HtL[c][kc]) = v;
            }
        }
        // P generation (8 entries per thread, one row strip)
        {
            const int* arow = A + arowOff + k0 + pc;
            i32x4 a0 = *(const i32x4*)(arow);
            i32x4 a1 = *(const i32x4*)(arow + 4);
            f32x4 r0 = *(const f32x4*)(rV + k0 + pc);
            f32x4 r1 = *(const f32x4*)(rV + k0 + pc + 4);
            short8 pk;
#pragma unroll
            for (int j = 0; j < 8; j++) {
                int aj = (j < 4) ? a0[j] : a1[j - 4];
                float rj = (j < 4) ? r0[j] : r1[j - 4];
                float x = sMine + rj;
                x = (x > 0.f) ? x : ALPHA * x;
                float p = aj ? __expf(x) : 0.f;
                dsum += p;
                pk[j] = (short)f32_to_bf16(p);
            }
            *(short8*)(&PL[pr][pc]) = pk;
        }
        __syncthreads();
        // MFMA: out[i0..+32][wave*64..+64] += P * Ht^T
#pragma unroll
        for (int ksx = 0; ksx < 2; ksx++) {
            const int kofs = ksx * 32 + 8 * lhi;
            short8 af0 = *(const short8*)(&PL[l15][kofs]);
            short8 af1 = *(const short8*)(&PL[16 + l15][kofs]);
#pragma unroll
            for (int n = 0; n < 4; n++) {
                short8 bf = *(const short8*)(&HtL[wave * 64 + n * 16 + l15][kofs]);
                acc[0][n] = __builtin_amdgcn_mfma_f32_16x16x32_bf16(af0, bf, acc[0][n], 0, 0, 0);
                acc[1][n] = __builtin_amdgcn_mfma_f32_16x16x32_bf16(af1, bf, acc[1][n], 0, 0, 0);
            }
        }
        __syncthreads();
    }

    // row denominators: reduce dsum over the 8 threads sharing pr
    dsum += __shfl_xor(dsum, 1, 64);
    dsum += __shfl_xor(dsum, 2, 64);
    dsum += __shfl_xor(dsum, 4, 64);
    if ((tid & 7) == 0) denomL[pr] = dsum;

    // dump accumulators: wave w's cols are head w, local col = n*16+l15
#pragma unroll
    for (int m = 0; m < 2; m++)
#pragma unroll
        for (int n = 0; n < 4; n++)
#pragma unroll
            for (int q = 0; q < 4; q++) {
                int row = m * 16 + lhi * 4 + q;
                int col = n * 16 + l15;
                outL[wave][row][col] = acc[m][n][q];
            }
    __syncthreads();

    // final: head-sum + divide, 8 outputs per thread
    const float inv = 1.0f / denomL[pr];
    float v[8];
#pragma unroll
    for (int j = 0; j < 8; j++) {
        int c = pc + j;
        v[j] = (outL[0][pr][c] + outL[1][pr][c] + outL[2][pr][c] + outL[3][pr][c]) * inv;
    }
    const size_t outOff = (size_t)(i0 + pr) * 64 + pc;
    if (*flag) {
        short8 pk;
#pragma unroll
        for (int j = 0; j < 8; j++) pk[j] = (short)f32_to_bf16(v[j]);
        *(short8*)((unsigned short*)outP + outOff) = pk;
    } else {
        float* o = (float*)outP + outOff;
        *(f32x4*)o = (f32x4){v[0], v[1], v[2], v[3]};
        *((f32x4*)o + 1) = (f32x4){v[4], v[5], v[6], v[7]};
    }
}

// ---------------- launch -----------------------------------------------------
extern "C" void kernel_launch(void* const* d_in, const int* in_sizes, int n_in,
                              void* d_out, int out_size, void* d_ws, size_t ws_size,
                              hipStream_t stream) {
    const void* X  = d_in[0];
    const int*  A  = (const int*)d_in[1];
    const void* W  = d_in[2];
    const void* bb = d_in[3];
    const void* as_ = d_in[4];
    const void* ar_ = d_in[5];

    char* ws = (char*)d_ws;
    const size_t OFF_FLAG = 0;
    const size_t OFF_XB   = 256;
    const size_t OFF_WB   = OFF_XB + (size_t)NN * 256 * 2;
    const size_t OFF_BF   = OFF_WB + (size_t)256 * 256 * 2;
    const size_t OFF_ASF  = OFF_BF + 1024;
    const size_t OFF_ARF  = OFF_ASF + 1024;
    const size_t OFF_S    = OFF_ARF + 1024;
    const size_t OFF_R    = OFF_S + (size_t)NN * 4;
    const size_t OFF_HT   = OFF_R + (size_t)NN * 4;

    int*   flag = (int*)(ws + OFF_FLAG);
    short* Xb   = (short*)(ws + OFF_XB);
    short* Wb   = (short*)(ws + OFF_WB);
    float* bF   = (float*)(ws + OFF_BF);
    float* asF  = (float*)(ws + OFF_ASF);
    float* arF  = (float*)(ws + OFF_ARF);
    float* sP   = (float*)(ws + OFF_S);
    float* rP   = (float*)(ws + OFF_R);
    short* Ht   = (short*)(ws + OFF_HT);

    gat_probe_dtype<<<1, 256, 0, stream>>>((const unsigned short*)X, flag);
    gat_convert<<<512, 256, 0, stream>>>(X, W, bb, as_, ar_, Xb, Wb, bF, asF, arF, flag);
    gat_gemm1<<<NN / 64, 256, 0, stream>>>(Xb, Wb, bF, asF, arF, Ht, sP, rP);
    gat_pv<<<NN / 32, 256, 0, stream>>>(A, Ht, sP, rP, flag, d_out);
}

// Round 2
// 130.328 us; speedup vs baseline: 1.9116x; 1.9116x over previous
//
#include <hip/hip_runtime.h>

typedef __attribute__((ext_vector_type(8))) short short8;
typedef __attribute__((ext_vector_type(4))) short short4v;
typedef __attribute__((ext_vector_type(4))) float f32x4;
typedef __attribute__((ext_vector_type(4))) int i32x4;

#define NN 8192
#define ALPHA 0.2f

__device__ __forceinline__ float bf16_to_f32(unsigned short h) {
    union { unsigned int u; float f; } c;
    c.u = ((unsigned int)h) << 16;
    return c.f;
}
__device__ __forceinline__ unsigned short f32_to_bf16(float f) {
    union { float f; unsigned int u; } c;
    c.f = f;
    unsigned int r = (c.u + 0x7FFFu + ((c.u >> 16) & 1u)) >> 16;
    return (unsigned short)r;
}

// ---------------- kernel 0: probe input dtype -------------------------------
// Interpret first 16K halves of X as bf16. bf16 normal data: ~100% in
// (1e-6, 64). f32 data: high halves pass (~100%), low halves ~11% -> ~55%.
__global__ void gat_probe_dtype(const unsigned short* __restrict__ x16, int* flag) {
    __shared__ int cnts[256];
    int tid = threadIdx.x;
    int cnt = 0;
    for (int i = tid; i < 16384; i += 256) {
        float v = bf16_to_f32(x16[i]);
        float a = fabsf(v);
        if (a > 1e-6f && a < 64.0f) cnt++;   // false for NaN too
    }
    cnts[tid] = cnt;
    __syncthreads();
    for (int s = 128; s > 0; s >>= 1) {
        if (tid < s) cnts[tid] += cnts[tid + s];
        __syncthreads();
    }
    if (tid == 0) *flag = (cnts[0] > 13000) ? 1 : 0;
}

// ---------------- kernel 1: convert inputs to ws copies ---------------------
__global__ void gat_convert(const void* __restrict__ Xv, const void* __restrict__ Wv,
                            const void* __restrict__ bv, const void* __restrict__ asv,
                            const void* __restrict__ arv,
                            short* __restrict__ Xb, short* __restrict__ Wb,
                            float* __restrict__ bF, float* __restrict__ asF,
                            float* __restrict__ arF, const int* __restrict__ flag) {
    const int NX = NN * 256, NW = 256 * 256, NS = 256;
    const int total = NX + NW + 3 * NS;
    const int isBf = *flag;
    for (int i = blockIdx.x * blockDim.x + threadIdx.x; i < total;
         i += gridDim.x * blockDim.x) {
        if (i < NX) {
            Xb[i] = isBf ? (short)((const unsigned short*)Xv)[i]
                         : (short)f32_to_bf16(((const float*)Xv)[i]);
        } else if (i < NX + NW) {
            int j = i - NX;
            Wb[j] = isBf ? (short)((const unsigned short*)Wv)[j]
                         : (short)f32_to_bf16(((const float*)Wv)[j]);
        } else {
            int j = i - NX - NW;
            int which = j >> 8;
            int k = j & 255;
            const void* src = (which == 0) ? bv : (which == 1) ? asv : arv;
            float v = isBf ? bf16_to_f32(((const unsigned short*)src)[k])
                           : ((const float*)src)[k];
            float* dst = (which == 0) ? bF : (which == 1) ? asF : arF;
            dst[k] = v;
        }
    }
}

// ---------------- kernel 2: H_in = X*W^T + b -> Gt, s, r ---------------------
// Same MFMA structure as before, but H_in itself is never stored: we emit
// Gt[o][row] = sum_h H_in[row][h*64+o] (bf16, k-major for the PV B-operand)
// plus s[row], r[row].
__global__ __launch_bounds__(256) void gat_gemm1(
    const short* __restrict__ Xb, const short* __restrict__ Wb,
    const float* __restrict__ bF, const float* __restrict__ asF,
    const float* __restrict__ arF,
    short* __restrict__ Gt, float* __restrict__ sOut, float* __restrict__ rOut) {
    const int tid = threadIdx.x;
    const int wave = tid >> 6, lane = tid & 63;
    const int l15 = lane & 15, lhi = lane >> 4;
    const int rowBase = blockIdx.x * 64 + wave * 16;

    f32x4 acc[16];
#pragma unroll
    for (int n = 0; n < 16; n++) acc[n] = (f32x4){0.f, 0.f, 0.f, 0.f};

    const short8* Xrow = (const short8*)(Xb + (size_t)(rowBase + l15) * 256);
#pragma unroll
    for (int ks = 0; ks < 8; ks++) {            // K = 256 in steps of 32
        short8 a = Xrow[ks * 4 + lhi];          // A[row=l15][k=ks*32+8*lhi ..+7]
#pragma unroll
        for (int n = 0; n < 16; n++) {
            const short8* Wrow = (const short8*)(Wb + (size_t)(n * 16 + l15) * 256);
            short8 bf = Wrow[ks * 4 + lhi];     // B[k][col=l15] = W[col][k]
            acc[n] = __builtin_amdgcn_mfma_f32_16x16x32_bf16(a, bf, acc[n], 0, 0, 0);
        }
    }

    float sPart[4] = {0.f, 0.f, 0.f, 0.f};
    float rPart[4] = {0.f, 0.f, 0.f, 0.f};
    float g[4][4];
#pragma unroll
    for (int na = 0; na < 4; na++)
#pragma unroll
        for (int q = 0; q < 4; q++) g[na][q] = 0.f;

#pragma unroll
    for (int n = 0; n < 16; n++) {
        int col = n * 16 + l15;
        float bias = bF[col], asc = asF[col], arc = arF[col];
#pragma unroll
        for (int q = 0; q < 4; q++) {
            float h = acc[n][q] + bias;         // D: row=lhi*4+q, col=l15
            sPart[q] += h * asc;
            rPart[q] += h * arc;
            g[n & 3][q] += h;                   // head-sum
        }
    }
    // Gt[o][rowBase + lhi*4 .. +3], o = na*16 + l15
#pragma unroll
    for (int na = 0; na < 4; na++) {
        short4v pk;
#pragma unroll
        for (int q = 0; q < 4; q++) pk[q] = (short)f32_to_bf16(g[na][q]);
        *(short4v*)(Gt + (size_t)(na * 16 + l15) * NN + rowBase + lhi * 4) = pk;
    }

#pragma unroll
    for (int m = 1; m <= 8; m <<= 1) {
#pragma unroll
        for (int q = 0; q < 4; q++) {
            sPart[q] += __shfl_xor(sPart[q], m, 64);
            rPart[q] += __shfl_xor(rPart[q], m, 64);
        }
    }
    if (l15 == 0) {
#pragma unroll
        for (int q = 0; q < 4; q++) {
            int row = rowBase + lhi * 4 + q;
            sOut[row] = sPart[q];
            rOut[row] = rPart[q];
        }
    }
}

// ---------------- kernel 3: fused masked-softmax PV (v2) --------------------
// Grid = 256 row-blocks x 4 K-slices. Block: rows i0..i0+31, K-chunk ks*2048.
// Each wave owns every-4th K-tile of 64 within the chunk: NO __syncthreads in
// the K-loop, per-wave private LDS P buffer, G fragments straight from L2.
// Epilogue: f32 atomicAdd into accG [N][64] and denomG [N].
__global__ __launch_bounds__(256, 4) void gat_pv2(
    const int* __restrict__ A, const short* __restrict__ Gt,
    const float* __restrict__ sV, const float* __restrict__ rV,
    float* __restrict__ accG, float* __restrict__ denomG) {
    __shared__ __align__(16) short PL[4][32][72];   // per-wave, pitch 144B

    const int tid = threadIdx.x;
    const int wave = tid >> 6, lane = tid & 63;
    const int l15 = lane & 15, lhi = lane >> 4;
    const int kq = lane & 15, rgroup = lane >> 4;   // P-gen mapping
    const int rb = blockIdx.x >> 2;
    const int ks = blockIdx.x & 3;
    const int i0 = rb * 32;

    float sreg[8];
#pragma unroll
    for (int r = 0; r < 8; r++) sreg[r] = sV[i0 + rgroup * 8 + r];

    float dreg[8] = {0.f, 0.f, 0.f, 0.f, 0.f, 0.f, 0.f, 0.f};
    f32x4 acc[2][4];
#pragma unroll
    for (int m = 0; m < 2; m++)
#pragma unroll
        for (int n = 0; n < 4; n++) acc[m][n] = (f32x4){0.f, 0.f, 0.f, 0.f};

    for (int t = 0; t < 8; t++) {
        const int kt = ks * 32 + t * 4 + wave;
        const int k0 = kt * 64;

        // A mask loads: 4 quarter-waves each read 256B contiguous per row
        i32x4 av[8];
        const int* abase = A + (size_t)(i0 + rgroup * 8) * NN + k0 + kq * 4;
#pragma unroll
        for (int r = 0; r < 8; r++) av[r] = *(const i32x4*)(abase + (size_t)r * NN);
        f32x4 rj = *(const f32x4*)(rV + k0 + kq * 4);

        // P = A ? exp(lrelu(s_i + r_j)) : 0  (bf16), transpose via LDS
#pragma unroll
        for (int r = 0; r < 8; r++) {
            short4v pk;
            float ds = 0.f;
#pragma unroll
            for (int j = 0; j < 4; j++) {
                float x = sreg[r] + rj[j];
                x = (x > 0.f) ? x : ALPHA * x;
                float e = __expf(x);
                e = av[r][j] ? e : 0.f;
                ds += e;
                pk[j] = (short)f32_to_bf16(e);
            }
            dreg[r] += ds;
            *(short4v*)(&PL[wave][rgroup * 8 + r][kq * 4]) = pk;
        }

        // MFMA: acc[32 rows][64 cols] += P * G ; B-frags from L2-resident Gt
#pragma unroll
        for (int ksx = 0; ksx < 2; ksx++) {
            const int ko = ksx * 32 + 8 * lhi;
            short8 af0 = *(const short8*)(&PL[wave][l15][ko]);
            short8 af1 = *(const short8*)(&PL[wave][16 + l15][ko]);
#pragma unroll
            for (int n = 0; n < 4; n++) {
                short8 bf = *(const short8*)(Gt + (size_t)(n * 16 + l15) * NN + k0 + ko);
                acc[0][n] = __builtin_amdgcn_mfma_f32_16x16x32_bf16(af0, bf, acc[0][n], 0, 0, 0);
                acc[1][n] = __builtin_amdgcn_mfma_f32_16x16x32_bf16(af1, bf, acc[1][n], 0, 0, 0);
            }
        }
    }

    // denominators: reduce over the 16 lanes sharing rgroup
#pragma unroll
    for (int m = 1; m <= 8; m <<= 1)
#pragma unroll
        for (int r = 0; r < 8; r++) dreg[r] += __shfl_xor(dreg[r], m, 64);
    if (kq == 0) {
#pragma unroll
        for (int r = 0; r < 8; r++)
            atomicAdd(&denomG[i0 + rgroup * 8 + r], dreg[r]);
    }

    // accumulator: atomic into global f32 buffer
#pragma unroll
    for (int m = 0; m < 2; m++)
#pragma unroll
        for (int n = 0; n < 4; n++)
#pragma unroll
            for (int q = 0; q < 4; q++) {
                int row = m * 16 + lhi * 4 + q;
                int col = n * 16 + l15;
                atomicAdd(&accG[(size_t)(i0 + row) * 64 + col], acc[m][n][q]);
            }
}

// ---------------- kernel 4: divide + dtype-cast output ----------------------
__global__ void gat_final(const float* __restrict__ accG, const float* __restrict__ denomG,
                          const int* __restrict__ flag, void* __restrict__ outP) {
    int idx = blockIdx.x * blockDim.x + threadIdx.x;  // one f32x4 group
    if (idx >= NN * 16) return;
    int row = idx >> 4;
    float inv = 1.0f / denomG[row];
    f32x4 v = *((const f32x4*)accG + idx);
    v.x *= inv; v.y *= inv; v.z *= inv; v.w *= inv;
    if (*flag) {
        short4v pk;
#pragma unroll
        for (int j = 0; j < 4; j++) pk[j] = (short)f32_to_bf16(v[j]);
        *((short4v*)outP + idx) = pk;
    } else {
        *((f32x4*)outP + idx) = v;
    }
}

// ---------------- launch -----------------------------------------------------
extern "C" void kernel_launch(void* const* d_in, const int* in_sizes, int n_in,
                              void* d_out, int out_size, void* d_ws, size_t ws_size,
                              hipStream_t stream) {
    const void* X  = d_in[0];
    const int*  A  = (const int*)d_in[1];
    const void* W  = d_in[2];
    const void* bb = d_in[3];
    const void* as_ = d_in[4];
    const void* ar_ = d_in[5];

    char* ws = (char*)d_ws;
    const size_t OFF_FLAG = 0;
    const size_t OFF_XB   = 256;
    const size_t OFF_WB   = OFF_XB + (size_t)NN * 256 * 2;
    const size_t OFF_BF   = OFF_WB + (size_t)256 * 256 * 2;
    const size_t OFF_ASF  = OFF_BF + 1024;
    const size_t OFF_ARF  = OFF_ASF + 1024;
    const size_t OFF_S    = OFF_ARF + 1024;
    const size_t OFF_R    = OFF_S + (size_t)NN * 4;
    const size_t OFF_GT   = OFF_R + (size_t)NN * 4;
    const size_t OFF_ACC  = OFF_GT + (size_t)64 * NN * 2;
    const size_t OFF_DEN  = OFF_ACC + (size_t)NN * 64 * 4;

    int*   flag = (int*)(ws + OFF_FLAG);
    short* Xb   = (short*)(ws + OFF_XB);
    short* Wb   = (short*)(ws + OFF_WB);
    float* bF   = (float*)(ws + OFF_BF);
    float* asF  = (float*)(ws + OFF_ASF);
    float* arF  = (float*)(ws + OFF_ARF);
    float* sP   = (float*)(ws + OFF_S);
    float* rP   = (float*)(ws + OFF_R);
    short* Gt   = (short*)(ws + OFF_GT);
    float* accG = (float*)(ws + OFF_ACC);
    float* denG = (float*)(ws + OFF_DEN);

    gat_probe_dtype<<<1, 256, 0, stream>>>((const unsigned short*)X, flag);
    gat_convert<<<512, 256, 0, stream>>>(X, W, bb, as_, ar_, Xb, Wb, bF, asF, arF, flag);
    hipMemsetAsync(ws + OFF_ACC, 0, (size_t)NN * 64 * 4 + (size_t)NN * 4, stream);
    gat_gemm1<<<NN / 64, 256, 0, stream>>>(Xb, Wb, bF, asF, arF, Gt, sP, rP);
    gat_pv2<<<(NN / 32) * 4, 256, 0, stream>>>(A, Gt, sP, rP, accG, denG);
    gat_final<<<NN * 16 / 256, 256, 0, stream>>>(accG, denG, flag, d_out);
}

// Round 3
// 117.650 us; speedup vs baseline: 2.1176x; 1.1078x over previous
//
#include <hip/hip_runtime.h>

typedef __attribute__((ext_vector_type(8))) short short8;
typedef __attribute__((ext_vector_type(4))) short short4v;
typedef __attribute__((ext_vector_type(4))) float f32x4;
typedef __attribute__((ext_vector_type(4))) int i32x4;

#define NN 8192
#define ALPHA 0.2f

__device__ __forceinline__ float bf16_to_f32(unsigned short h) {
    union { unsigned int u; float f; } c;
    c.u = ((unsigned int)h) << 16;
    return c.f;
}
__device__ __forceinline__ unsigned short f32_to_bf16(float f) {
    union { float f; unsigned int u; } c;
    c.f = f;
    unsigned int r = (c.u + 0x7FFFu + ((c.u >> 16) & 1u)) >> 16;
    return (unsigned short)r;
}

// ---------------- kernel 0: probe input dtype -------------------------------
__global__ void gat_probe_dtype(const unsigned short* __restrict__ x16, int* flag) {
    __shared__ int cnts[256];
    int tid = threadIdx.x;
    int cnt = 0;
    for (int i = tid; i < 16384; i += 256) {
        float v = bf16_to_f32(x16[i]);
        float a = fabsf(v);
        if (a > 1e-6f && a < 64.0f) cnt++;   // false for NaN too
    }
    cnts[tid] = cnt;
    __syncthreads();
    for (int s = 128; s > 0; s >>= 1) {
        if (tid < s) cnts[tid] += cnts[tid + s];
        __syncthreads();
    }
    if (tid == 0) *flag = (cnts[0] > 13000) ? 1 : 0;
}

// ---------------- kernel 1: convert inputs to ws copies (vectorized) --------
__global__ void gat_convert(const void* __restrict__ Xv, const void* __restrict__ Wv,
                            const void* __restrict__ bv, const void* __restrict__ asv,
                            const void* __restrict__ arv,
                            short* __restrict__ Xb, short* __restrict__ Wb,
                            float* __restrict__ bF, float* __restrict__ asF,
                            float* __restrict__ arF, const int* __restrict__ flag) {
    const int GX = NN * 256 / 8;      // short8 groups in X
    const int GW = 256 * 256 / 8;     // short8 groups in W
    const int isBf = *flag;
    const int idx = blockIdx.x * blockDim.x + threadIdx.x;
    const int stride = gridDim.x * blockDim.x;
    for (int i = idx; i < GX + GW; i += stride) {
        const void* src = (i < GX) ? Xv : Wv;
        short* dst = (i < GX) ? Xb : Wb;
        int g = (i < GX) ? i : i - GX;
        short8 o;
        if (isBf) {
            o = ((const short8*)src)[g];
        } else {
            f32x4 a = ((const f32x4*)src)[2 * g];
            f32x4 b = ((const f32x4*)src)[2 * g + 1];
#pragma unroll
            for (int j = 0; j < 4; j++) {
                o[j] = (short)f32_to_bf16(a[j]);
                o[4 + j] = (short)f32_to_bf16(b[j]);
            }
        }
        ((short8*)dst)[g] = o;
    }
    if (idx < 768) {
        int which = idx >> 8;
        int k = idx & 255;
        const void* src = (which == 0) ? bv : (which == 1) ? asv : arv;
        float v = isBf ? bf16_to_f32(((const unsigned short*)src)[k])
                       : ((const float*)src)[k];
        float* dst = (which == 0) ? bF : (which == 1) ? asF : arF;
        dst[k] = v;
    }
}

// ---------------- kernel 2: H_in = X*W^T + b -> Gt, s, r ---------------------
// 256 blocks x 128 threads (2 waves, 16 rows each). Gt[o][row] = head-sum,
// bf16, k-major for the PV B-operand; s[row], r[row] f32.
__global__ __launch_bounds__(128) void gat_gemm1(
    const short* __restrict__ Xb, const short* __restrict__ Wb,
    const float* __restrict__ bF, const float* __restrict__ asF,
    const float* __restrict__ arF,
    short* __restrict__ Gt, float* __restrict__ sOut, float* __restrict__ rOut) {
    const int tid = threadIdx.x;
    const int wave = tid >> 6, lane = tid & 63;
    const int l15 = lane & 15, lhi = lane >> 4;
    const int rowBase = blockIdx.x * 32 + wave * 16;

    f32x4 acc[16];
#pragma unroll
    for (int n = 0; n < 16; n++) acc[n] = (f32x4){0.f, 0.f, 0.f, 0.f};

    const short8* Xrow = (const short8*)(Xb + (size_t)(rowBase + l15) * 256);
#pragma unroll
    for (int ks = 0; ks < 8; ks++) {            // K = 256 in steps of 32
        short8 a = Xrow[ks * 4 + lhi];
#pragma unroll
        for (int n = 0; n < 16; n++) {
            const short8* Wrow = (const short8*)(Wb + (size_t)(n * 16 + l15) * 256);
            short8 bf = Wrow[ks * 4 + lhi];
            acc[n] = __builtin_amdgcn_mfma_f32_16x16x32_bf16(a, bf, acc[n], 0, 0, 0);
        }
    }

    float sPart[4] = {0.f, 0.f, 0.f, 0.f};
    float rPart[4] = {0.f, 0.f, 0.f, 0.f};
    float g[4][4];
#pragma unroll
    for (int na = 0; na < 4; na++)
#pragma unroll
        for (int q = 0; q < 4; q++) g[na][q] = 0.f;

#pragma unroll
    for (int n = 0; n < 16; n++) {
        int col = n * 16 + l15;
        float bias = bF[col], asc = asF[col], arc = arF[col];
#pragma unroll
        for (int q = 0; q < 4; q++) {
            float h = acc[n][q] + bias;         // D: row=lhi*4+q, col=l15
            sPart[q] += h * asc;
            rPart[q] += h * arc;
            g[n & 3][q] += h;                   // head-sum
        }
    }
#pragma unroll
    for (int na = 0; na < 4; na++) {
        short4v pk;
#pragma unroll
        for (int q = 0; q < 4; q++) pk[q] = (short)f32_to_bf16(g[na][q]);
        *(short4v*)(Gt + (size_t)(na * 16 + l15) * NN + rowBase + lhi * 4) = pk;
    }

#pragma unroll
    for (int m = 1; m <= 8; m <<= 1) {
#pragma unroll
        for (int q = 0; q < 4; q++) {
            sPart[q] += __shfl_xor(sPart[q], m, 64);
            rPart[q] += __shfl_xor(rPart[q], m, 64);
        }
    }
    if (l15 == 0) {
#pragma unroll
        for (int q = 0; q < 4; q++) {
            int row = rowBase + lhi * 4 + q;
            sOut[row] = sPart[q];
            rOut[row] = rPart[q];
        }
    }
}

// ---------------- kernel 3: fused masked-softmax PV (v3) --------------------
// Grid = 256 row-blocks x 4 K-slices. Block rows i0..i0+31.
// Wave w = (wm, wk): wm picks 16-row half, wk picks 1024-wide k-half; each
// wave walks 16 contiguous 64-k tiles (sequential 256B/row chunks). No
// block-wide syncs, no atomics: partial sums to accP[sk][N][64], denP[sk][N],
// sk = ks*2+wk (8 slices). A loads are non-temporal (keep Gt L2-resident).
__global__ __launch_bounds__(256) void gat_pv3(
    const int* __restrict__ A, const short* __restrict__ Gt,
    const float* __restrict__ sV, const float* __restrict__ rV,
    float* __restrict__ accP, float* __restrict__ denP) {
    __shared__ __align__(16) short PL[4][16][72];   // per-wave 16-row P tile

    const int tid = threadIdx.x;
    const int wave = tid >> 6, lane = tid & 63;
    const int l15 = lane & 15, lhi = lane >> 4;
    const int kq = lane & 15, rgroup = lane >> 4;
    const int wm = wave >> 1, wk = wave & 1;
    const int rb = blockIdx.x >> 2;
    const int ks = blockIdx.x & 3;
    const int i0 = rb * 32;
    const int sk = ks * 2 + wk;
    const int rowTop = i0 + wm * 16;

    f32x4 sreg = *(const f32x4*)(sV + rowTop + rgroup * 4);
    f32x4 dreg = (f32x4){0.f, 0.f, 0.f, 0.f};
    f32x4 acc[4];
#pragma unroll
    for (int n = 0; n < 4; n++) acc[n] = (f32x4){0.f, 0.f, 0.f, 0.f};

    const int* abase0 = A + (size_t)(rowTop + rgroup * 4) * NN + kq * 4;

    for (int t = 0; t < 16; t++) {
        const int k0 = (ks * 32 + wk * 16 + t) * 64;

        // A mask: 4 rows x 16 lanes x 16B (contiguous 256B per row)
        i32x4 av[4];
        const int* abase = abase0 + k0;
#pragma unroll
        for (int r = 0; r < 4; r++)
            av[r] = __builtin_nontemporal_load((const i32x4*)(abase + (size_t)r * NN));
        f32x4 rj = *(const f32x4*)(rV + k0 + kq * 4);

        // P = A ? exp(lrelu(s_i + r_j)) : 0  (bf16) -> per-wave LDS
#pragma unroll
        for (int r = 0; r < 4; r++) {
            short4v pk;
            float ds = 0.f;
#pragma unroll
            for (int j = 0; j < 4; j++) {
                float x = sreg[r] + rj[j];
                x = fmaxf(x, ALPHA * x);        // leaky-relu
                float e = __expf(x);
                e = av[r][j] ? e : 0.f;
                ds += e;
                pk[j] = (short)f32_to_bf16(e);
            }
            dreg[r] += ds;
            *(short4v*)(&PL[wave][rgroup * 4 + r][kq * 4]) = pk;
        }

        // MFMA: acc[16 rows][64 cols] += P * G
#pragma unroll
        for (int ksx = 0; ksx < 2; ksx++) {
            const int ko = ksx * 32 + 8 * lhi;
            short8 af = *(const short8*)(&PL[wave][l15][ko]);
#pragma unroll
            for (int n = 0; n < 4; n++) {
                short8 bf = *(const short8*)(Gt + (size_t)(n * 16 + l15) * NN + k0 + ko);
                acc[n] = __builtin_amdgcn_mfma_f32_16x16x32_bf16(af, bf, acc[n], 0, 0, 0);
            }
        }
    }

    // denominators: reduce over 16 lanes sharing rgroup, store partial
#pragma unroll
    for (int m = 1; m <= 8; m <<= 1)
#pragma unroll
        for (int r = 0; r < 4; r++) dreg[r] += __shfl_xor(dreg[r], m, 64);
    if (kq == 0) {
#pragma unroll
        for (int r = 0; r < 4; r++)
            denP[(size_t)sk * NN + rowTop + rgroup * 4 + r] = dreg[r];
    }

    // partial accumulator store (disjoint per slice, coalesced 64B/quarter)
    float* aout = accP + (size_t)sk * NN * 64;
#pragma unroll
    for (int n = 0; n < 4; n++)
#pragma unroll
        for (int q = 0; q < 4; q++)
            aout[(size_t)(rowTop + lhi * 4 + q) * 64 + n * 16 + l15] = acc[n][q];
}

// ---------------- kernel 4: sum 8 partials, divide, cast --------------------
__global__ void gat_final(const float* __restrict__ accP, const float* __restrict__ denP,
                          const int* __restrict__ flag, void* __restrict__ outP) {
    int idx = blockIdx.x * blockDim.x + threadIdx.x;  // one f32x4 group
    if (idx >= NN * 16) return;
    int row = idx >> 4;
    float den = 0.f;
    f32x4 v = (f32x4){0.f, 0.f, 0.f, 0.f};
#pragma unroll
    for (int sk = 0; sk < 8; sk++) {
        den += denP[(size_t)sk * NN + row];
        f32x4 a = *((const f32x4*)(accP + (size_t)sk * NN * 64) + idx);
        v.x += a.x; v.y += a.y; v.z += a.z; v.w += a.w;
    }
    float inv = 1.0f / den;
    v.x *= inv; v.y *= inv; v.z *= inv; v.w *= inv;
    if (*flag) {
        short4v pk;
#pragma unroll
        for (int j = 0; j < 4; j++) pk[j] = (short)f32_to_bf16(v[j]);
        *((short4v*)outP + idx) = pk;
    } else {
        *((f32x4*)outP + idx) = v;
    }
}

// ---------------- launch -----------------------------------------------------
extern "C" void kernel_launch(void* const* d_in, const int* in_sizes, int n_in,
                              void* d_out, int out_size, void* d_ws, size_t ws_size,
                              hipStream_t stream) {
    const void* X  = d_in[0];
    const int*  A  = (const int*)d_in[1];
    const void* W  = d_in[2];
    const void* bb = d_in[3];
    const void* as_ = d_in[4];
    const void* ar_ = d_in[5];

    char* ws = (char*)d_ws;
    const size_t OFF_FLAG = 0;
    const size_t OFF_XB   = 256;
    const size_t OFF_WB   = OFF_XB + (size_t)NN * 256 * 2;
    const size_t OFF_BF   = OFF_WB + (size_t)256 * 256 * 2;
    const size_t OFF_ASF  = OFF_BF + 1024;
    const size_t OFF_ARF  = OFF_ASF + 1024;
    const size_t OFF_S    = OFF_ARF + 1024;
    const size_t OFF_R    = OFF_S + (size_t)NN * 4;
    const size_t OFF_GT   = OFF_R + (size_t)NN * 4;
    const size_t OFF_ACC  = OFF_GT + (size_t)64 * NN * 2;
    const size_t OFF_DEN  = OFF_ACC + (size_t)8 * NN * 64 * 4;

    int*   flag = (int*)(ws + OFF_FLAG);
    short* Xb   = (short*)(ws + OFF_XB);
    short* Wb   = (short*)(ws + OFF_WB);
    float* bF   = (float*)(ws + OFF_BF);
    float* asF  = (float*)(ws + OFF_ASF);
    float* arF  = (float*)(ws + OFF_ARF);
    float* sP   = (float*)(ws + OFF_S);
    float* rP   = (float*)(ws + OFF_R);
    short* Gt   = (short*)(ws + OFF_GT);
    float* accP = (float*)(ws + OFF_ACC);
    float* denP = (float*)(ws + OFF_DEN);

    gat_probe_dtype<<<1, 256, 0, stream>>>((const unsigned short*)X, flag);
    gat_convert<<<512, 256, 0, stream>>>(X, W, bb, as_, ar_, Xb, Wb, bF, asF, arF, flag);
    gat_gemm1<<<NN / 32, 128, 0, stream>>>(Xb, Wb, bF, asF, arF, Gt, sP, rP);
    gat_pv3<<<(NN / 32) * 4, 256, 0, stream>>>(A, Gt, sP, rP, accP, denP);
    gat_final<<<NN * 16 / 256, 256, 0, stream>>>(accP, denP, flag, d_out);
}